// Round 10
// baseline (474.039 us; speedup 1.0000x reference)
//
#include <hip/hip_runtime.h>
#include <math.h>

#define N_NODES 100000
#define N_EDGES 2500000
#define N_GRAPHS 512
#define IN_DIM 14
#define HID 32
#define CAP 64        // per-node slot capacity; degree ~ Poisson(25), max ~55

// dst-buckets: bucket = dst >> 7 (128 nodes each)  [R7 build config]
#define BSHIFT 7
#define BNODES 128
#define NB 782        // ceil(100000/128)
#define NBP 784
#define BCAP 4096
#define SUBCAP 1024   // 4 banks
#define CHUNK 4096
#define NBLK_E ((N_EDGES + CHUNK - 1) / CHUNK)   // 612

#define GCUR_N 3200   // >= NB*4 = 3128  (R9 bug: was 1600 -> poison cursors -> OOB)
#define TSZ 1600016   // ushorts per half-table: exactly (N+1)*16, 16B-aligned

typedef unsigned int uint;
typedef unsigned short ushort;

__device__ inline float bflo(uint w) { return __uint_as_float(w << 16); }
__device__ inline float bfhi(uint w) { return __uint_as_float(w & 0xffff0000u); }
__device__ inline ushort f2bf(float f) {
    uint u = __float_as_uint(f);
    return (ushort)((u + 0x7fffu + ((u >> 16) & 1u)) >> 16);  // RNE
}
__device__ inline uint pk(float a, float b) {
    return (uint)f2bf(a) | ((uint)f2bf(b) << 16);
}

// ============ pass 1: coarse-bin edges by dst bucket (dense run writes) =======
__global__ void bin_edges(const int* __restrict__ src, const int* __restrict__ dst,
                          int* __restrict__ gcur, int* __restrict__ binned) {
    __shared__ int scnt[NBP];
    __shared__ int sbase[NBP];
    __shared__ int soff[NBP];
    int t = threadIdx.x;
    for (int i = t; i < NBP; i += 256) { scnt[i] = 0; soff[i] = 0; }
    __syncthreads();
    int base = blockIdx.x * CHUNK;
    int bank = blockIdx.x & 3;
    for (int j = 0; j < CHUNK; j += 256) {
        int e = base + j + t;
        if (e < N_EDGES) atomicAdd(&scnt[dst[e] >> BSHIFT], 1);
    }
    __syncthreads();
    for (int b = t; b < NBP; b += 256) {
        int c = scnt[b];
        sbase[b] = (c > 0) ? atomicAdd(&gcur[b * 4 + bank], c) : 0;
    }
    __syncthreads();
    for (int j = 0; j < CHUNK; j += 256) {
        int e = base + j + t;
        if (e < N_EDGES) {
            int d = dst[e];
            int b = d >> BSHIFT;
            int pos = sbase[b] + atomicAdd(&soff[b], 1);
            if (pos < SUBCAP)
                binned[b * BCAP + bank * SUBCAP + pos] = (src[e] << BSHIFT) | (d & (BNODES - 1));
        }
    }
}

// ============ pass 2: 128x64 slot tile in LDS (dummy-padded), line-granular out ==
__global__ void build_slots(const int* __restrict__ gcur, const int* __restrict__ binned,
                            int* __restrict__ deg, int* __restrict__ slots) {
    __shared__ int stile[BNODES * CAP];  // 32 KB
    __shared__ int sdeg[BNODES];
    int t = threadIdx.x;
    for (int i = t; i < BNODES * CAP; i += 256) stile[i] = N_NODES;  // dummy pad
    if (t < BNODES) sdeg[t] = 0;
    __syncthreads();
    int b = blockIdx.x;
#pragma unroll
    for (int k = 0; k < 4; ++k) {
        int cnt = gcur[b * 4 + k]; if (cnt > SUBCAP) cnt = SUBCAP;
        const int* seg = binned + b * BCAP + k * SUBCAP;
        for (int i = t; i < cnt; i += 256) {
            int w = seg[i];
            int ld = w & (BNODES - 1), sn = w >> BSHIFT;
            int p = atomicAdd(&sdeg[ld], 1);
            if (p < CAP) stile[ld * CAP + p] = sn;
        }
    }
    __syncthreads();
    int nbase = b * BNODES;
    int rows = N_NODES - nbase; if (rows > BNODES) rows = BNODES;
    int r = t & 127, h = t >> 7;           // 2 threads per row
    if (r < rows) {
        int dv = sdeg[r]; if (dv > CAP) dv = CAP;
        if (h == 0) deg[nbase + r] = dv;
        int n4 = ((dv + 15) >> 4) << 2;    // int4s covering whole 64B lines (incl. pad)
        int4* drow = (int4*)(slots + (size_t)(nbase + r) * CAP);
        const int4* srow = (const int4*)(stile + r * CAP);
        for (int i = h; i < n4; i += 2) drow[i] = srow[i];
    }
}

// ============ layer-1 pre-GEMM: T_A = x @ W_rel1 as two bf16 half-tables ========
__global__ void gemm14(const float* __restrict__ h, const float* __restrict__ W,
                       ushort* __restrict__ TA0, ushort* __restrict__ TA1,
                       ushort* __restrict__ TB0, ushort* __restrict__ TB1) {
    __shared__ float sW[IN_DIM][HID];
    int t = threadIdx.x;
    for (int i = t; i < IN_DIM * HID; i += 256) sW[i / HID][i % HID] = W[i];
    if (blockIdx.x == 0 && t < 8) {        // zero dummy row N_NODES in all 4 tables
        ushort* tb = (t < 2) ? TA0 : (t < 4) ? TA1 : (t < 6) ? TB0 : TB1;
        ((uint4*)(tb + (size_t)N_NODES * 16))[t & 1] = make_uint4(0, 0, 0, 0);
    }
    __syncthreads();
    int idx = blockIdx.x * 256 + t;
    if (idx >= N_NODES * HID) return;
    int n = idx >> 5, o = idx & 31;
    const float* hr = h + (long)n * IN_DIM;
    float acc = 0.f;
#pragma unroll
    for (int k = 0; k < IN_DIM; ++k) acc += hr[k] * sW[k][o];
    if (o < 16) TA0[(size_t)n * 16 + o] = f2bf(acc);
    else        TA1[(size_t)n * 16 + (o - 16)] = f2bf(acc);
}

// ============ fused conv, phase-split gather ============
// 2 lanes per node (128 nodes/block). Phase H gathers half-table T_H (3.2 MB,
// L2-resident); lane p owns features {p*8..p*8+7} ∪ {16+p*8..16+p*8+7}.
// Epilogue: bias + root(h_in@Wroot) + relu -> h_out; optionally tmp_next =
// h_out@Wrel_next written to the next layer's half-tables.
template <int KROOT, bool ROOT_BF16, bool MAKE_TOUT>
__global__ void conv2(const int* __restrict__ deg, const int* __restrict__ slots,
                      const ushort* __restrict__ T0, const ushort* __restrict__ T1,
                      const void* __restrict__ hin,      // N x KROOT (f32) or N x 32 (bf16)
                      const float* __restrict__ bias,    // 32
                      const float* __restrict__ Wroot,   // KROOT x 32
                      const float* __restrict__ WrelN,   // 32 x 32 (if MAKE_TOUT)
                      ushort* __restrict__ hout,         // N x 32 bf16
                      ushort* __restrict__ TO0, ushort* __restrict__ TO1) {
    __shared__ float sWroot[KROOT * HID];
    __shared__ float sWrelN[MAKE_TOUT ? HID * HID : 1];
    __shared__ float sb[HID];
    int t = threadIdx.x;
    for (int i = t; i < KROOT * HID; i += 256) sWroot[i] = Wroot[i];
    if (MAKE_TOUT)
        for (int i = t; i < HID * HID; i += 256) sWrelN[i] = WrelN[i];
    if (t < HID) sb[t] = bias[t];
    __syncthreads();

    int n = blockIdx.x * 128 + (t >> 1);
    if (n >= N_NODES) return;
    int p = t & 1;

    int dn = deg[n]; if (dn > CAP) dn = CAP;
    int rounds = (dn + 7) >> 3;
    const int* sl = slots + (size_t)n * CAP;

    float r[16];
#pragma unroll
    for (int i = 0; i < 16; ++i) r[i] = 0.f;

#pragma unroll
    for (int H = 0; H < 2; ++H) {
        const ushort* T = H ? T1 : T0;
        for (int rr = 0; rr < rounds; ++rr) {
            int4 my = *(const int4*)(sl + rr * 8 + p * 4);
            int mc[4] = {my.x, my.y, my.z, my.w};
#pragma unroll
            for (int j = 0; j < 8; ++j) {
                int c = __shfl(mc[j & 3], j >> 2, 2);   // edge j's src (dummy if pad)
                const uint4 v = *(const uint4*)(T + (size_t)c * 16 + p * 8);
                r[H * 8 + 0] += bflo(v.x); r[H * 8 + 1] += bfhi(v.x);
                r[H * 8 + 2] += bflo(v.y); r[H * 8 + 3] += bfhi(v.y);
                r[H * 8 + 4] += bflo(v.z); r[H * 8 + 5] += bfhi(v.z);
                r[H * 8 + 6] += bflo(v.w); r[H * 8 + 7] += bfhi(v.w);
            }
        }
    }

    // bias
#pragma unroll
    for (int i = 0; i < 8; ++i) {
        r[i]     += sb[p * 8 + i];
        r[8 + i] += sb[16 + p * 8 + i];
    }

    // root term
    if constexpr (ROOT_BF16) {
        const uint4* hp = (const uint4*)((const ushort*)hin + (size_t)n * HID + p * 16);
        uint4 h0 = hp[0], h1 = hp[1];
        float hh[16] = {bflo(h0.x), bfhi(h0.x), bflo(h0.y), bfhi(h0.y),
                        bflo(h0.z), bfhi(h0.z), bflo(h0.w), bfhi(h0.w),
                        bflo(h1.x), bfhi(h1.x), bflo(h1.y), bfhi(h1.y),
                        bflo(h1.z), bfhi(h1.z), bflo(h1.w), bfhi(h1.w)};
#pragma unroll
        for (int k = 0; k < HID; ++k) {
            float hv = __shfl(hh[k & 15], k >> 4, 2);
            const float* w = &sWroot[k * HID];
#pragma unroll
            for (int i = 0; i < 8; ++i) {
                r[i]     += hv * w[p * 8 + i];
                r[8 + i] += hv * w[16 + p * 8 + i];
            }
        }
    } else {
        const float* hr = (const float*)hin + (size_t)n * KROOT;
#pragma unroll
        for (int k = 0; k < KROOT; ++k) {
            float hv = hr[k];
            const float* w = &sWroot[k * HID];
#pragma unroll
            for (int i = 0; i < 8; ++i) {
                r[i]     += hv * w[p * 8 + i];
                r[8 + i] += hv * w[16 + p * 8 + i];
            }
        }
    }

    // relu
#pragma unroll
    for (int i = 0; i < 16; ++i) r[i] = fmaxf(r[i], 0.f);

    // write h_out (full row, two 16B stores per lane)
    *(uint4*)(hout + (size_t)n * HID + p * 8) =
        make_uint4(pk(r[0], r[1]), pk(r[2], r[3]), pk(r[4], r[5]), pk(r[6], r[7]));
    *(uint4*)(hout + (size_t)n * HID + 16 + p * 8) =
        make_uint4(pk(r[8], r[9]), pk(r[10], r[11]), pk(r[12], r[13]), pk(r[14], r[15]));

    // tmp_next = h_out @ Wrel_next -> half-tables
    if constexpr (MAKE_TOUT) {
        float to[16];
#pragma unroll
        for (int i = 0; i < 16; ++i) to[i] = 0.f;
#pragma unroll
        for (int k = 0; k < HID; ++k) {
            int owner = (k & 15) >> 3;
            int lidx = (k < 16) ? (k & 7) : (8 + (k & 7));
            float hv = __shfl(r[lidx], owner, 2);
            const float* w = &sWrelN[k * HID];
#pragma unroll
            for (int i = 0; i < 8; ++i) {
                to[i]     += hv * w[p * 8 + i];
                to[8 + i] += hv * w[16 + p * 8 + i];
            }
        }
        *(uint4*)(TO0 + (size_t)n * 16 + p * 8) =
            make_uint4(pk(to[0], to[1]), pk(to[2], to[3]), pk(to[4], to[5]), pk(to[6], to[7]));
        *(uint4*)(TO1 + (size_t)n * 16 + p * 8) =
            make_uint4(pk(to[8], to[9]), pk(to[10], to[11]), pk(to[12], to[13]), pk(to[14], to[15]));
    }
}

// ============ sum pool per graph (batch sorted -> run-length accumulate) ======
#define POOL_NODES 128
__global__ void pool_sum(const ushort* __restrict__ h, const int* __restrict__ batch,
                         float* __restrict__ g) {
    __shared__ int sbatch[POOL_NODES];
    int t = threadIdx.x;
    int nbase = blockIdx.x * POOL_NODES;
    for (int i = t; i < POOL_NODES; i += 256) {
        int n = nbase + i;
        sbatch[i] = (n < N_NODES) ? batch[n] : -1;
    }
    __syncthreads();
    int f = t & 31;
    int c0 = (t >> 5) * 16;
    int curb = -1;
    float acc = 0.f;
    for (int j = 0; j < 16; ++j) {
        int li = c0 + j;
        int n = nbase + li;
        if (n >= N_NODES) break;
        int bid = sbatch[li];
        float v = bflo((uint)h[(size_t)n * HID + f]);
        if (bid != curb) {
            if (curb >= 0) atomicAdd(&g[curb * HID + f], acc);
            curb = bid;
            acc = 0.f;
        }
        acc += v;
    }
    if (curb >= 0) atomicAdd(&g[curb * HID + f], acc);
}

// ============ head: relu(g@W1+b1) @ W2 + b2 -> log_softmax ============
__global__ void head(const float* __restrict__ g, const float* __restrict__ w1,
                     const float* __restrict__ b1, const float* __restrict__ w2,
                     const float* __restrict__ b2, float* __restrict__ out) {
    __shared__ float sW1[HID][HID];
    __shared__ float sW2[HID][2];
    __shared__ float sb1[HID];
    int t = threadIdx.x;  // 512 threads, one graph each
    for (int i = t; i < HID * HID; i += 512) sW1[i / HID][i % HID] = w1[i];
    if (t < HID * 2) sW2[t / 2][t % 2] = w2[t];
    if (t < HID) sb1[t] = b1[t];
    __syncthreads();
    float gi[HID];
#pragma unroll
    for (int k = 0; k < HID; ++k) gi[k] = g[t * HID + k];
    float l0 = b2[0], l1 = b2[1];
#pragma unroll
    for (int o = 0; o < HID; ++o) {
        float a = sb1[o];
#pragma unroll
        for (int k = 0; k < HID; ++k) a += gi[k] * sW1[k][o];
        a = fmaxf(a, 0.f);
        l0 += a * sW2[o][0];
        l1 += a * sW2[o][1];
    }
    float m = fmaxf(l0, l1);
    float lse = m + logf(expf(l0 - m) + expf(l1 - m));
    out[t * 2 + 0] = l0 - lse;
    out[t * 2 + 1] = l1 - lse;
}

extern "C" void kernel_launch(void* const* d_in, const int* in_sizes, int n_in,
                              void* d_out, int out_size, void* d_ws, size_t ws_size,
                              hipStream_t stream) {
    const float* x      = (const float*)d_in[0];
    const float* W_rel1 = (const float*)d_in[1];
    const float* b_rel1 = (const float*)d_in[2];
    const float* W_root1= (const float*)d_in[3];
    const float* W_rel  = (const float*)d_in[4];   // 4 x 32 x 32
    const float* b_rel  = (const float*)d_in[5];   // 4 x 32
    const float* W_root = (const float*)d_in[6];   // 4 x 32 x 32
    const float* lin1_w = (const float*)d_in[7];
    const float* lin1_b = (const float*)d_in[8];
    const float* lin2_w = (const float*)d_in[9];
    const float* lin2_b = (const float*)d_in[10];
    const int*   ei     = (const int*)d_in[11];    // [2, E]: src then dst
    const int*   batch  = (const int*)d_in[12];
    float* out = (float*)d_out;

    const int* src = ei;
    const int* dst = ei + N_EDGES;

    // workspace layout (16B alignment at every vector-accessed region)
    int*    gcur   = (int*)d_ws;                        // GCUR_N ints (>= NB*4)
    int*    binned = gcur + GCUR_N;                     // NB*BCAP ints (12.8 MB)
    int*    deg    = binned + NB * BCAP;                // N pad N+32
    int*    slots  = deg + N_NODES + 32;                // N * CAP (25.6 MB)
    ushort* TA0    = (ushort*)(slots + (size_t)N_NODES * CAP);
    ushort* TA1    = TA0 + TSZ;
    ushort* TB0    = TA1 + TSZ;
    ushort* TB1    = TB0 + TSZ;
    float*  g      = (float*)(TB1 + TSZ);               // 512*32 f32
    // h ping-pong overlays binned (dead after build_slots): 2 x 6.4 MB = 12.8 MB
    ushort* HA     = (ushort*)binned;
    ushort* HB     = HA + (size_t)N_NODES * HID;

    dim3 blk(256);
    dim3 grd_no((N_NODES * HID + 255) / 256);  // 12500
    dim3 grd_cv((N_NODES + 127) / 128);        // 782
    dim3 grd_pl((N_NODES + POOL_NODES - 1) / POOL_NODES);

    // ---- two-pass slot-table build ----
    hipMemsetAsync(gcur, 0, GCUR_N * sizeof(int), stream);
    bin_edges<<<dim3(NBLK_E), blk, 0, stream>>>(src, dst, gcur, binned);
    build_slots<<<dim3(NB), blk, 0, stream>>>(gcur, binned, deg, slots);

    // ---- T_A = x @ W_rel1 (half-tables) + zero all dummy rows ----
    gemm14<<<grd_no, blk, 0, stream>>>(x, W_rel1, TA0, TA1, TB0, TB1);

    // ---- layer 1: gather T_A, root = x @ W_root1; also emit T_B = h1@W_rel[0] ----
    conv2<IN_DIM, false, true><<<grd_cv, blk, 0, stream>>>(
        deg, slots, TA0, TA1, (const void*)x, b_rel1, W_root1, W_rel, HA, TB0, TB1);

    // ---- layer 2: gather T_B, root h1; emit T_A = h2@W_rel[1] ----
    conv2<HID, true, true><<<grd_cv, blk, 0, stream>>>(
        deg, slots, TB0, TB1, (const void*)HA, b_rel, W_root, W_rel + 1 * HID * HID,
        HB, TA0, TA1);
    // ---- layer 3 ----
    conv2<HID, true, true><<<grd_cv, blk, 0, stream>>>(
        deg, slots, TA0, TA1, (const void*)HB, b_rel + HID, W_root + 1 * HID * HID,
        W_rel + 2 * HID * HID, HA, TB0, TB1);
    // ---- layer 4 ----
    conv2<HID, true, true><<<grd_cv, blk, 0, stream>>>(
        deg, slots, TB0, TB1, (const void*)HA, b_rel + 2 * HID, W_root + 2 * HID * HID,
        W_rel + 3 * HID * HID, HB, TA0, TA1);
    // ---- layer 5 (no T emit) ----
    conv2<HID, true, false><<<grd_cv, blk, 0, stream>>>(
        deg, slots, TA0, TA1, (const void*)HB, b_rel + 3 * HID, W_root + 3 * HID * HID,
        nullptr, HA, nullptr, nullptr);

    // ---- sum pool + head ----
    hipMemsetAsync(g, 0, (size_t)N_GRAPHS * HID * sizeof(float), stream);
    pool_sum<<<grd_pl, blk, 0, stream>>>(HA, batch, g);
    head<<<dim3(1), dim3(512), 0, stream>>>(g, lin1_w, lin1_b, lin2_w, lin2_b, out);
}

// Round 11
// 470.753 us; speedup vs baseline: 1.0070x; 1.0070x over previous
//
#include <hip/hip_runtime.h>
#include <math.h>

#define N_NODES 100000
#define N_EDGES 2500000
#define N_GRAPHS 512
#define IN_DIM 14
#define HID 32
#define CAP 64        // per-node slot capacity; degree ~ Poisson(25), max ~55

// dst-buckets: bucket = dst >> 7 (128 nodes each)
#define BSHIFT 7
#define BNODES 128
#define NB 782        // ceil(100000/128)
#define NBP 784
#define BCAP 4096
#define SUBCAP 1024   // 4 banks
#define CHUNK 4096
#define NBLK_E ((N_EDGES + CHUNK - 1) / CHUNK)   // 612

#define GCUR_N 3200   // >= NB*4 = 3128
#define TSZ 1600016   // ushorts per half-table: exactly (N+1)*16, 16B-aligned

typedef unsigned int uint;
typedef unsigned short ushort;

__device__ inline float bflo(uint w) { return __uint_as_float(w << 16); }
__device__ inline float bfhi(uint w) { return __uint_as_float(w & 0xffff0000u); }
__device__ inline ushort f2bf(float f) {
    uint u = __float_as_uint(f);
    return (ushort)((u + 0x7fffu + ((u >> 16) & 1u)) >> 16);  // RNE
}
__device__ inline uint pk(float a, float b) {
    return (uint)f2bf(a) | ((uint)f2bf(b) << 16);
}

// ============ pass 1: coarse-bin edges by dst bucket (dense run writes) =======
__global__ void bin_edges(const int* __restrict__ src, const int* __restrict__ dst,
                          int* __restrict__ gcur, int* __restrict__ binned) {
    __shared__ int scnt[NBP];
    __shared__ int sbase[NBP];
    __shared__ int soff[NBP];
    int t = threadIdx.x;
    for (int i = t; i < NBP; i += 256) { scnt[i] = 0; soff[i] = 0; }
    __syncthreads();
    int base = blockIdx.x * CHUNK;
    int bank = blockIdx.x & 3;
    for (int j = 0; j < CHUNK; j += 256) {
        int e = base + j + t;
        if (e < N_EDGES) atomicAdd(&scnt[dst[e] >> BSHIFT], 1);
    }
    __syncthreads();
    for (int b = t; b < NBP; b += 256) {
        int c = scnt[b];
        sbase[b] = (c > 0) ? atomicAdd(&gcur[b * 4 + bank], c) : 0;
    }
    __syncthreads();
    for (int j = 0; j < CHUNK; j += 256) {
        int e = base + j + t;
        if (e < N_EDGES) {
            int d = dst[e];
            int b = d >> BSHIFT;
            int pos = sbase[b] + atomicAdd(&soff[b], 1);
            if (pos < SUBCAP)
                binned[b * BCAP + bank * SUBCAP + pos] = (src[e] << BSHIFT) | (d & (BNODES - 1));
        }
    }
}

// ============ pass 2: 128x64 slot tile in LDS (dummy-padded), line-granular out ==
__global__ void build_slots(const int* __restrict__ gcur, const int* __restrict__ binned,
                            int* __restrict__ deg, int* __restrict__ slots) {
    __shared__ int stile[BNODES * CAP];  // 32 KB
    __shared__ int sdeg[BNODES];
    int t = threadIdx.x;
    for (int i = t; i < BNODES * CAP; i += 256) stile[i] = N_NODES;  // dummy pad
    if (t < BNODES) sdeg[t] = 0;
    __syncthreads();
    int b = blockIdx.x;
#pragma unroll
    for (int k = 0; k < 4; ++k) {
        int cnt = gcur[b * 4 + k]; if (cnt > SUBCAP) cnt = SUBCAP;
        const int* seg = binned + b * BCAP + k * SUBCAP;
        for (int i = t; i < cnt; i += 256) {
            int w = seg[i];
            int ld = w & (BNODES - 1), sn = w >> BSHIFT;
            int p = atomicAdd(&sdeg[ld], 1);
            if (p < CAP) stile[ld * CAP + p] = sn;
        }
    }
    __syncthreads();
    int nbase = b * BNODES;
    int rows = N_NODES - nbase; if (rows > BNODES) rows = BNODES;
    int r = t & 127, h = t >> 7;           // 2 threads per row
    if (r < rows) {
        int dv = sdeg[r]; if (dv > CAP) dv = CAP;
        if (h == 0) deg[nbase + r] = dv;
        int n4 = ((dv + 15) >> 4) << 2;    // int4s covering whole 64B lines (incl. pad)
        int4* drow = (int4*)(slots + (size_t)(nbase + r) * CAP);
        const int4* srow = (const int4*)(stile + r * CAP);
        for (int i = h; i < n4; i += 2) drow[i] = srow[i];
    }
}

// ============ layer-1 pre-GEMM: T_A = x @ W_rel1 as two bf16 half-tables ========
__global__ void gemm14(const float* __restrict__ h, const float* __restrict__ W,
                       ushort* __restrict__ TA0, ushort* __restrict__ TA1,
                       ushort* __restrict__ TB0, ushort* __restrict__ TB1) {
    __shared__ float sW[IN_DIM][HID];
    int t = threadIdx.x;
    for (int i = t; i < IN_DIM * HID; i += 256) sW[i / HID][i % HID] = W[i];
    if (blockIdx.x == 0 && t < 8) {        // zero dummy row N_NODES in all 4 tables
        ushort* tb = (t < 2) ? TA0 : (t < 4) ? TA1 : (t < 6) ? TB0 : TB1;
        ((uint4*)(tb + (size_t)N_NODES * 16))[t & 1] = make_uint4(0, 0, 0, 0);
    }
    __syncthreads();
    int idx = blockIdx.x * 256 + t;
    if (idx >= N_NODES * HID) return;
    int n = idx >> 5, o = idx & 31;
    const float* hr = h + (long)n * IN_DIM;
    float acc = 0.f;
#pragma unroll
    for (int k = 0; k < IN_DIM; ++k) acc += hr[k] * sW[k][o];
    if (o < 16) TA0[(size_t)n * 16 + o] = f2bf(acc);
    else        TA1[(size_t)n * 16 + (o - 16)] = f2bf(acc);
}

// ============ fused conv, phase-split gather, 4 lanes/node ============
// 64 nodes/block (1563 blocks -> 6 blocks/CU). Phase H gathers half-table T_H;
// lane q owns features {q*4..q*4+3} of each half. Epilogue: bias + root + relu
// -> h_out; optionally tmp_next = h_out@Wrel_next -> next layer's half-tables.
template <int KROOT, bool ROOT_BF16, bool MAKE_TOUT>
__global__ void conv3(const int* __restrict__ deg, const int* __restrict__ slots,
                      const ushort* __restrict__ T0, const ushort* __restrict__ T1,
                      const void* __restrict__ hin,      // N x KROOT (f32) or N x 32 (bf16)
                      const float* __restrict__ bias,    // 32
                      const float* __restrict__ Wroot,   // KROOT x 32
                      const float* __restrict__ WrelN,   // 32 x 32 (if MAKE_TOUT)
                      ushort* __restrict__ hout,         // N x 32 bf16
                      ushort* __restrict__ TO0, ushort* __restrict__ TO1) {
    __shared__ float sWroot[KROOT * HID];
    __shared__ float sWrelN[MAKE_TOUT ? HID * HID : 1];
    __shared__ float sb[HID];
    int t = threadIdx.x;
    for (int i = t; i < KROOT * HID; i += 256) sWroot[i] = Wroot[i];
    if (MAKE_TOUT)
        for (int i = t; i < HID * HID; i += 256) sWrelN[i] = WrelN[i];
    if (t < HID) sb[t] = bias[t];
    __syncthreads();

    int n = blockIdx.x * 64 + (t >> 2);
    if (n >= N_NODES) return;
    int q = t & 3;

    int dn = deg[n]; if (dn > CAP) dn = CAP;
    int rounds = (dn + 7) >> 3;
    const int* sl = slots + (size_t)n * CAP;

    float r[8];
#pragma unroll
    for (int i = 0; i < 8; ++i) r[i] = 0.f;

    // phase 0: gather T0 -> r[0..3]
    for (int rr = 0; rr < rounds; ++rr) {
        int2 my = *(const int2*)(sl + rr * 8 + q * 2);
#pragma unroll
        for (int j = 0; j < 8; ++j) {
            int c = __shfl((j & 1) ? my.y : my.x, j >> 1, 4);
            const uint2 v = *(const uint2*)(T0 + (size_t)c * 16 + q * 4);
            r[0] += bflo(v.x); r[1] += bfhi(v.x);
            r[2] += bflo(v.y); r[3] += bfhi(v.y);
        }
    }
    // phase 1: gather T1 -> r[4..7]
    for (int rr = 0; rr < rounds; ++rr) {
        int2 my = *(const int2*)(sl + rr * 8 + q * 2);
#pragma unroll
        for (int j = 0; j < 8; ++j) {
            int c = __shfl((j & 1) ? my.y : my.x, j >> 1, 4);
            const uint2 v = *(const uint2*)(T1 + (size_t)c * 16 + q * 4);
            r[4] += bflo(v.x); r[5] += bfhi(v.x);
            r[6] += bflo(v.y); r[7] += bfhi(v.y);
        }
    }

    // bias
#pragma unroll
    for (int i = 0; i < 4; ++i) {
        r[i]     += sb[q * 4 + i];
        r[4 + i] += sb[16 + q * 4 + i];
    }

    // root term
    if constexpr (ROOT_BF16) {
        uint4 h4 = *(const uint4*)((const ushort*)hin + (size_t)n * HID + q * 8);
        float hh[8] = {bflo(h4.x), bfhi(h4.x), bflo(h4.y), bfhi(h4.y),
                       bflo(h4.z), bfhi(h4.z), bflo(h4.w), bfhi(h4.w)};
#pragma unroll
        for (int cl = 0; cl < 4; ++cl) {
#pragma unroll
            for (int j = 0; j < 8; ++j) {
                float hv = __shfl(hh[j], cl, 4);         // h[k], k = cl*8+j
                const float* w = &sWroot[(cl * 8 + j) * HID];
#pragma unroll
                for (int i = 0; i < 4; ++i) {
                    r[i]     += hv * w[q * 4 + i];
                    r[4 + i] += hv * w[16 + q * 4 + i];
                }
            }
        }
    } else {
        const float* hr = (const float*)hin + (size_t)n * KROOT;
#pragma unroll
        for (int k = 0; k < KROOT; ++k) {
            float hv = hr[k];
            const float* w = &sWroot[k * HID];
#pragma unroll
            for (int i = 0; i < 4; ++i) {
                r[i]     += hv * w[q * 4 + i];
                r[4 + i] += hv * w[16 + q * 4 + i];
            }
        }
    }

    // relu
#pragma unroll
    for (int i = 0; i < 8; ++i) r[i] = fmaxf(r[i], 0.f);

    // write h_out full row: lane q covers features q*4..+3 and 16+q*4..+3
    *(uint2*)(hout + (size_t)n * HID + q * 4) = make_uint2(pk(r[0], r[1]), pk(r[2], r[3]));
    *(uint2*)(hout + (size_t)n * HID + 16 + q * 4) = make_uint2(pk(r[4], r[5]), pk(r[6], r[7]));

    // tmp_next = h_out @ Wrel_next -> half-tables
    if constexpr (MAKE_TOUT) {
        float to[8];
#pragma unroll
        for (int i = 0; i < 8; ++i) to[i] = 0.f;
#pragma unroll
        for (int k = 0; k < HID; ++k) {
            int kk = k & 15;
            int owner = kk >> 2;
            int lidx = (k < 16) ? (kk & 3) : 4 + (kk & 3);
            float hv = __shfl(r[lidx], owner, 4);        // h_out[k]
            const float* w = &sWrelN[k * HID];
#pragma unroll
            for (int i = 0; i < 4; ++i) {
                to[i]     += hv * w[q * 4 + i];
                to[4 + i] += hv * w[16 + q * 4 + i];
            }
        }
        *(uint2*)(TO0 + (size_t)n * 16 + q * 4) = make_uint2(pk(to[0], to[1]), pk(to[2], to[3]));
        *(uint2*)(TO1 + (size_t)n * 16 + q * 4) = make_uint2(pk(to[4], to[5]), pk(to[6], to[7]));
    }
}

// ============ sum pool per graph (batch sorted -> run-length accumulate) ======
#define POOL_NODES 128
__global__ void pool_sum(const ushort* __restrict__ h, const int* __restrict__ batch,
                         float* __restrict__ g) {
    __shared__ int sbatch[POOL_NODES];
    int t = threadIdx.x;
    int nbase = blockIdx.x * POOL_NODES;
    for (int i = t; i < POOL_NODES; i += 256) {
        int n = nbase + i;
        sbatch[i] = (n < N_NODES) ? batch[n] : -1;
    }
    __syncthreads();
    int f = t & 31;
    int c0 = (t >> 5) * 16;
    int curb = -1;
    float acc = 0.f;
    for (int j = 0; j < 16; ++j) {
        int li = c0 + j;
        int n = nbase + li;
        if (n >= N_NODES) break;
        int bid = sbatch[li];
        float v = bflo((uint)h[(size_t)n * HID + f]);
        if (bid != curb) {
            if (curb >= 0) atomicAdd(&g[curb * HID + f], acc);
            curb = bid;
            acc = 0.f;
        }
        acc += v;
    }
    if (curb >= 0) atomicAdd(&g[curb * HID + f], acc);
}

// ============ head: relu(g@W1+b1) @ W2 + b2 -> log_softmax ============
__global__ void head(const float* __restrict__ g, const float* __restrict__ w1,
                     const float* __restrict__ b1, const float* __restrict__ w2,
                     const float* __restrict__ b2, float* __restrict__ out) {
    __shared__ float sW1[HID][HID];
    __shared__ float sW2[HID][2];
    __shared__ float sb1[HID];
    int t = threadIdx.x;  // 512 threads, one graph each
    for (int i = t; i < HID * HID; i += 512) sW1[i / HID][i % HID] = w1[i];
    if (t < HID * 2) sW2[t / 2][t % 2] = w2[t];
    if (t < HID) sb1[t] = b1[t];
    __syncthreads();
    float gi[HID];
#pragma unroll
    for (int k = 0; k < HID; ++k) gi[k] = g[t * HID + k];
    float l0 = b2[0], l1 = b2[1];
#pragma unroll
    for (int o = 0; o < HID; ++o) {
        float a = sb1[o];
#pragma unroll
        for (int k = 0; k < HID; ++k) a += gi[k] * sW1[k][o];
        a = fmaxf(a, 0.f);
        l0 += a * sW2[o][0];
        l1 += a * sW2[o][1];
    }
    float m = fmaxf(l0, l1);
    float lse = m + logf(expf(l0 - m) + expf(l1 - m));
    out[t * 2 + 0] = l0 - lse;
    out[t * 2 + 1] = l1 - lse;
}

extern "C" void kernel_launch(void* const* d_in, const int* in_sizes, int n_in,
                              void* d_out, int out_size, void* d_ws, size_t ws_size,
                              hipStream_t stream) {
    const float* x      = (const float*)d_in[0];
    const float* W_rel1 = (const float*)d_in[1];
    const float* b_rel1 = (const float*)d_in[2];
    const float* W_root1= (const float*)d_in[3];
    const float* W_rel  = (const float*)d_in[4];   // 4 x 32 x 32
    const float* b_rel  = (const float*)d_in[5];   // 4 x 32
    const float* W_root = (const float*)d_in[6];   // 4 x 32 x 32
    const float* lin1_w = (const float*)d_in[7];
    const float* lin1_b = (const float*)d_in[8];
    const float* lin2_w = (const float*)d_in[9];
    const float* lin2_b = (const float*)d_in[10];
    const int*   ei     = (const int*)d_in[11];    // [2, E]: src then dst
    const int*   batch  = (const int*)d_in[12];
    float* out = (float*)d_out;

    const int* src = ei;
    const int* dst = ei + N_EDGES;

    // workspace layout (16B alignment at every vector-accessed region)
    int*    gcur   = (int*)d_ws;                        // GCUR_N ints (>= NB*4)
    int*    binned = gcur + GCUR_N;                     // NB*BCAP ints (12.8 MB)
    int*    deg    = binned + NB * BCAP;                // N pad N+32
    int*    slots  = deg + N_NODES + 32;                // N * CAP (25.6 MB)
    ushort* TA0    = (ushort*)(slots + (size_t)N_NODES * CAP);
    ushort* TA1    = TA0 + TSZ;
    ushort* TB0    = TA1 + TSZ;
    ushort* TB1    = TB0 + TSZ;
    float*  g      = (float*)(TB1 + TSZ);               // 512*32 f32
    // h ping-pong overlays binned (dead after build_slots): 2 x 6.4 MB = 12.8 MB
    ushort* HA     = (ushort*)binned;
    ushort* HB     = HA + (size_t)N_NODES * HID;

    dim3 blk(256);
    dim3 grd_no((N_NODES * HID + 255) / 256);  // 12500
    dim3 grd_cv((N_NODES + 63) / 64);          // 1563
    dim3 grd_pl((N_NODES + POOL_NODES - 1) / POOL_NODES);

    // ---- two-pass slot-table build ----
    hipMemsetAsync(gcur, 0, GCUR_N * sizeof(int), stream);
    bin_edges<<<dim3(NBLK_E), blk, 0, stream>>>(src, dst, gcur, binned);
    build_slots<<<dim3(NB), blk, 0, stream>>>(gcur, binned, deg, slots);

    // ---- T_A = x @ W_rel1 (half-tables) + zero all dummy rows ----
    gemm14<<<grd_no, blk, 0, stream>>>(x, W_rel1, TA0, TA1, TB0, TB1);

    // ---- layer 1: gather T_A, root = x @ W_root1; also emit T_B = h1@W_rel[0] ----
    conv3<IN_DIM, false, true><<<grd_cv, blk, 0, stream>>>(
        deg, slots, TA0, TA1, (const void*)x, b_rel1, W_root1, W_rel, HA, TB0, TB1);

    // ---- layer 2: gather T_B, root h1; emit T_A = h2@W_rel[1] ----
    conv3<HID, true, true><<<grd_cv, blk, 0, stream>>>(
        deg, slots, TB0, TB1, (const void*)HA, b_rel, W_root, W_rel + 1 * HID * HID,
        HB, TA0, TA1);
    // ---- layer 3 ----
    conv3<HID, true, true><<<grd_cv, blk, 0, stream>>>(
        deg, slots, TA0, TA1, (const void*)HB, b_rel + HID, W_root + 1 * HID * HID,
        W_rel + 2 * HID * HID, HA, TB0, TB1);
    // ---- layer 4 ----
    conv3<HID, true, true><<<grd_cv, blk, 0, stream>>>(
        deg, slots, TB0, TB1, (const void*)HA, b_rel + 2 * HID, W_root + 2 * HID * HID,
        W_rel + 3 * HID * HID, HB, TA0, TA1);
    // ---- layer 5 (no T emit) ----
    conv3<HID, true, false><<<grd_cv, blk, 0, stream>>>(
        deg, slots, TA0, TA1, (const void*)HB, b_rel + 3 * HID, W_root + 3 * HID * HID,
        nullptr, HA, nullptr, nullptr);

    // ---- sum pool + head ----
    hipMemsetAsync(g, 0, (size_t)N_GRAPHS * HID * sizeof(float), stream);
    pool_sum<<<grd_pl, blk, 0, stream>>>(HA, batch, g);
    head<<<dim3(1), dim3(512), 0, stream>>>(g, lin1_w, lin1_b, lin2_w, lin2_b, out);
}

// Round 12
// 388.563 us; speedup vs baseline: 1.2200x; 1.2115x over previous
//
#include <hip/hip_runtime.h>
#include <math.h>

#define N_NODES 100000
#define N_EDGES 2500000
#define N_GRAPHS 512
#define IN_DIM 14
#define HID 32
#define CAP 64        // per-node slot capacity; degree ~ Poisson(25), max ~55

// dst-buckets: bucket = dst >> 7 (128 nodes each)
#define BSHIFT 7
#define BNODES 128
#define NB 782        // ceil(100000/128)
#define NBP 784
#define BCAP 4096
#define SUBCAP 1024   // 4 banks
#define CHUNK 4096
#define NBLK_E ((N_EDGES + CHUNK - 1) / CHUNK)   // 612

#define GSTRIDE 16                     // one 64B line per (bucket,bank) cursor
#define GCUR_N (NBP * 4 * GSTRIDE)     // 50176 ints = 200 KB

typedef unsigned int uint;
typedef unsigned short ushort;

__device__ inline float bflo(uint w) { return __uint_as_float(w << 16); }
__device__ inline float bfhi(uint w) { return __uint_as_float(w & 0xffff0000u); }
__device__ inline ushort f2bf(float f) {
    uint u = __float_as_uint(f);
    return (ushort)((u + 0x7fffu + ((u >> 16) & 1u)) >> 16);  // RNE
}

// ============ pass 1: coarse-bin edges by dst bucket (dense run writes) =======
// cursors padded to 64B/line -> atomic chain per line = blocks/4 = 153
__global__ void bin_edges(const int* __restrict__ src, const int* __restrict__ dst,
                          int* __restrict__ gcur, int* __restrict__ binned) {
    __shared__ int scnt[NBP];
    __shared__ int sbase[NBP];
    __shared__ int soff[NBP];
    int t = threadIdx.x;
    for (int i = t; i < NBP; i += 256) { scnt[i] = 0; soff[i] = 0; }
    __syncthreads();
    int base = blockIdx.x * CHUNK;
    int bank = blockIdx.x & 3;
    for (int j = 0; j < CHUNK; j += 256) {
        int e = base + j + t;
        if (e < N_EDGES) atomicAdd(&scnt[dst[e] >> BSHIFT], 1);
    }
    __syncthreads();
    for (int b = t; b < NBP; b += 256) {
        int c = scnt[b];
        sbase[b] = (c > 0) ? atomicAdd(&gcur[(b * 4 + bank) * GSTRIDE], c) : 0;
    }
    __syncthreads();
    for (int j = 0; j < CHUNK; j += 256) {
        int e = base + j + t;
        if (e < N_EDGES) {
            int d = dst[e];
            int b = d >> BSHIFT;
            int pos = sbase[b] + atomicAdd(&soff[b], 1);
            if (pos < SUBCAP)
                binned[b * BCAP + bank * SUBCAP + pos] = (src[e] << BSHIFT) | (d & (BNODES - 1));
        }
    }
}

// ============ pass 2: 128x64 slot tile in LDS (dummy-padded), line-granular out ==
__global__ void build_slots(const int* __restrict__ gcur, const int* __restrict__ binned,
                            int* __restrict__ deg, int* __restrict__ slots) {
    __shared__ int stile[BNODES * CAP];  // 32 KB
    __shared__ int sdeg[BNODES];
    int t = threadIdx.x;
    for (int i = t; i < BNODES * CAP; i += 256) stile[i] = N_NODES;  // dummy pad
    if (t < BNODES) sdeg[t] = 0;
    __syncthreads();
    int b = blockIdx.x;
#pragma unroll
    for (int k = 0; k < 4; ++k) {
        int cnt = gcur[(b * 4 + k) * GSTRIDE]; if (cnt > SUBCAP) cnt = SUBCAP;
        const int* seg = binned + b * BCAP + k * SUBCAP;
        for (int i = t; i < cnt; i += 256) {
            int w = seg[i];
            int ld = w & (BNODES - 1), sn = w >> BSHIFT;
            int p = atomicAdd(&sdeg[ld], 1);
            if (p < CAP) stile[ld * CAP + p] = sn;
        }
    }
    __syncthreads();
    int nbase = b * BNODES;
    int rows = N_NODES - nbase; if (rows > BNODES) rows = BNODES;
    int r = t & 127, h = t >> 7;           // 2 threads per row
    if (r < rows) {
        int dv = sdeg[r]; if (dv > CAP) dv = CAP;
        if (h == 0) deg[nbase + r] = dv;
        int n4 = ((dv + 15) >> 4) << 2;    // int4s covering whole 64B lines (incl. pad)
        int4* drow = (int4*)(slots + (size_t)(nbase + r) * CAP);
        const int4* srow = (const int4*)(stile + r * CAP);
        for (int i = h; i < n4; i += 2) drow[i] = srow[i];
    }
}

// ============ layer-1 pre-GEMM: tmp(bf16) = x @ W_rel1; zero dummy rows ========
__global__ void gemm14(const float* __restrict__ h, const float* __restrict__ W,
                       ushort* __restrict__ out, ushort* __restrict__ zrow2) {
    __shared__ float sW[IN_DIM][HID];
    int t = threadIdx.x;
    for (int i = t; i < IN_DIM * HID; i += 256) sW[i / HID][i % HID] = W[i];
    if (blockIdx.x == 0) {   // zero dummy row N_NODES in both bf16 tables
        if (t < 4) ((uint4*)(out + (size_t)N_NODES * HID))[t] = make_uint4(0, 0, 0, 0);
        else if (t < 8) ((uint4*)(zrow2 + (size_t)N_NODES * HID))[t - 4] = make_uint4(0, 0, 0, 0);
    }
    __syncthreads();
    int idx = blockIdx.x * 256 + t;
    if (idx >= N_NODES * HID) return;
    int n = idx >> 5, o = idx & 31;
    const float* hr = h + (long)n * IN_DIM;
    float acc = 0.f;
#pragma unroll
    for (int k = 0; k < IN_DIM; ++k) acc += hr[k] * sW[k][o];
    out[idx] = f2bf(acc);
}

// ============ fused conv (R8 structure, best measured): 4 lanes/node, uint4 ====
// Rounds of 8 edges; slot rows dummy-padded to round-8 -> mask-free inner loop.
template <bool MUL_REL, int K, bool ROOT_BF16>
__global__ void conv_fused(const int* __restrict__ deg, const int* __restrict__ slots,
                           const ushort* __restrict__ featb,  // (N+1) x 32 bf16 table
                           const void* __restrict__ root_in,  // N x K (bf16 or f32)
                           const float* __restrict__ Wrel,    // 32x32 (if MUL_REL)
                           const float* __restrict__ bias,    // 32
                           const float* __restrict__ Wroot,   // K x 32
                           ushort* __restrict__ outb) {       // (N+1) x 32 bf16
    __shared__ float sWrel[MUL_REL ? HID * HID : 1];
    __shared__ float sWroot[K * HID];
    __shared__ float sb[HID];
    int t = threadIdx.x;
    if (MUL_REL)
        for (int i = t; i < HID * HID; i += 256) sWrel[i] = Wrel[i];
    for (int i = t; i < K * HID; i += 256) sWroot[i] = Wroot[i];
    if (t < HID) sb[t] = bias[t];
    __syncthreads();

    int n = blockIdx.x * 64 + (t >> 2);
    if (n >= N_NODES) return;
    int q = t & 3;           // lane in 4-group: owns features q*8 .. q*8+7

    int dn = deg[n]; if (dn > CAP) dn = CAP;
    int rounds = (dn + 7) >> 3;
    const int* sl = slots + (size_t)n * CAP;
    float a[8] = {0.f, 0.f, 0.f, 0.f, 0.f, 0.f, 0.f, 0.f};
    for (int r = 0; r < rounds; ++r) {
        int2 my = *(const int2*)(sl + r * 8 + q * 2);  // coalesced slot preload
#pragma unroll
        for (int j = 0; j < 8; ++j) {
            int c = __shfl((j & 1) ? my.y : my.x, j >> 1, 4);  // dummy row if padded
            uint4 v = *(const uint4*)(featb + (size_t)c * HID + q * 8);
            a[0] += bflo(v.x); a[1] += bfhi(v.x);
            a[2] += bflo(v.y); a[3] += bfhi(v.y);
            a[4] += bflo(v.z); a[5] += bfhi(v.z);
            a[6] += bflo(v.w); a[7] += bfhi(v.w);
        }
    }

    float r8[8];
#pragma unroll
    for (int o = 0; o < 8; ++o) r8[o] = sb[q * 8 + o];

    if constexpr (MUL_REL) {
#pragma unroll
        for (int cl = 0; cl < 4; ++cl) {
#pragma unroll
            for (int j = 0; j < 8; ++j) {
                float av = __shfl(a[j], cl, 4);
                const float* w = &sWrel[(cl * 8 + j) * HID + q * 8];
#pragma unroll
                for (int o = 0; o < 8; ++o) r8[o] += av * w[o];
            }
        }
    } else {
#pragma unroll
        for (int o = 0; o < 8; ++o) r8[o] += a[o];
    }

    if constexpr (ROOT_BF16) {
        uint4 h4 = *(const uint4*)((const ushort*)root_in + (size_t)n * HID + q * 8);
        float hh[8] = {bflo(h4.x), bfhi(h4.x), bflo(h4.y), bfhi(h4.y),
                       bflo(h4.z), bfhi(h4.z), bflo(h4.w), bfhi(h4.w)};
#pragma unroll
        for (int cl = 0; cl < 4; ++cl) {
#pragma unroll
            for (int j = 0; j < 8; ++j) {
                float hv = __shfl(hh[j], cl, 4);
                const float* w = &sWroot[(cl * 8 + j) * HID + q * 8];
#pragma unroll
                for (int o = 0; o < 8; ++o) r8[o] += hv * w[o];
            }
        }
    } else {
        const float* hr = (const float*)root_in + (long)n * K;
#pragma unroll
        for (int k = 0; k < K; ++k) {
            float hv = hr[k];
            const float* w = &sWroot[k * HID + q * 8];
#pragma unroll
            for (int o = 0; o < 8; ++o) r8[o] += hv * w[o];
        }
    }

    uint pw[4];
#pragma unroll
    for (int m = 0; m < 4; ++m)
        pw[m] = (uint)f2bf(fmaxf(r8[2 * m], 0.f)) |
                ((uint)f2bf(fmaxf(r8[2 * m + 1], 0.f)) << 16);
    *(uint4*)(outb + (size_t)n * HID + q * 8) = make_uint4(pw[0], pw[1], pw[2], pw[3]);
}

// ============ sum pool per graph (batch sorted -> run-length accumulate) ======
#define POOL_NODES 128
__global__ void pool_sum(const ushort* __restrict__ h, const int* __restrict__ batch,
                         float* __restrict__ g) {
    __shared__ int sbatch[POOL_NODES];
    int t = threadIdx.x;
    int nbase = blockIdx.x * POOL_NODES;
    for (int i = t; i < POOL_NODES; i += 256) {
        int n = nbase + i;
        sbatch[i] = (n < N_NODES) ? batch[n] : -1;
    }
    __syncthreads();
    int f = t & 31;
    int c0 = (t >> 5) * 16;
    int curb = -1;
    float acc = 0.f;
    for (int j = 0; j < 16; ++j) {
        int li = c0 + j;
        int n = nbase + li;
        if (n >= N_NODES) break;
        int bid = sbatch[li];
        float v = bflo((uint)h[(size_t)n * HID + f]);
        if (bid != curb) {
            if (curb >= 0) atomicAdd(&g[curb * HID + f], acc);
            curb = bid;
            acc = 0.f;
        }
        acc += v;
    }
    if (curb >= 0) atomicAdd(&g[curb * HID + f], acc);
}

// ============ head: relu(g@W1+b1) @ W2 + b2 -> log_softmax ============
__global__ void head(const float* __restrict__ g, const float* __restrict__ w1,
                     const float* __restrict__ b1, const float* __restrict__ w2,
                     const float* __restrict__ b2, float* __restrict__ out) {
    __shared__ float sW1[HID][HID];
    __shared__ float sW2[HID][2];
    __shared__ float sb1[HID];
    int t = threadIdx.x;  // 512 threads, one graph each
    for (int i = t; i < HID * HID; i += 512) sW1[i / HID][i % HID] = w1[i];
    if (t < HID * 2) sW2[t / 2][t % 2] = w2[t];
    if (t < HID) sb1[t] = b1[t];
    __syncthreads();
    float gi[HID];
#pragma unroll
    for (int k = 0; k < HID; ++k) gi[k] = g[t * HID + k];
    float l0 = b2[0], l1 = b2[1];
#pragma unroll
    for (int o = 0; o < HID; ++o) {
        float a = sb1[o];
#pragma unroll
        for (int k = 0; k < HID; ++k) a += gi[k] * sW1[k][o];
        a = fmaxf(a, 0.f);
        l0 += a * sW2[o][0];
        l1 += a * sW2[o][1];
    }
    float m = fmaxf(l0, l1);
    float lse = m + logf(expf(l0 - m) + expf(l1 - m));
    out[t * 2 + 0] = l0 - lse;
    out[t * 2 + 1] = l1 - lse;
}

extern "C" void kernel_launch(void* const* d_in, const int* in_sizes, int n_in,
                              void* d_out, int out_size, void* d_ws, size_t ws_size,
                              hipStream_t stream) {
    const float* x      = (const float*)d_in[0];
    const float* W_rel1 = (const float*)d_in[1];
    const float* b_rel1 = (const float*)d_in[2];
    const float* W_root1= (const float*)d_in[3];
    const float* W_rel  = (const float*)d_in[4];   // 4 x 32 x 32
    const float* b_rel  = (const float*)d_in[5];   // 4 x 32
    const float* W_root = (const float*)d_in[6];   // 4 x 32 x 32
    const float* lin1_w = (const float*)d_in[7];
    const float* lin1_b = (const float*)d_in[8];
    const float* lin2_w = (const float*)d_in[9];
    const float* lin2_b = (const float*)d_in[10];
    const int*   ei     = (const int*)d_in[11];    // [2, E]: src then dst
    const int*   batch  = (const int*)d_in[12];
    float* out = (float*)d_out;

    const int* src = ei;
    const int* dst = ei + N_EDGES;

    // workspace layout (16B alignment at every vector-accessed region)
    int*    gcur   = (int*)d_ws;                        // GCUR_N ints (200 KB)
    int*    binned = gcur + GCUR_N;                     // NB*BCAP ints (12.8 MB)
    int*    deg    = binned + NB * BCAP;                // N pad N+32
    int*    slots  = deg + N_NODES + 32;                // N * CAP (25.6 MB)
    ushort* B0b    = (ushort*)(slots + (size_t)N_NODES * CAP);  // (N+1)*32 bf16
    ushort* B1b    = B0b + (size_t)(N_NODES + 1) * HID;         // (N+1)*32 bf16
    float*  g      = (float*)(B1b + (size_t)(N_NODES + 1) * HID);  // 512*32 f32

    dim3 blk(256);
    dim3 grd_no((N_NODES * HID + 255) / 256);  // 12500
    dim3 grd_cv((N_NODES + 63) / 64);          // 1563
    dim3 grd_pl((N_NODES + POOL_NODES - 1) / POOL_NODES);

    // ---- two-pass slot-table build ----
    hipMemsetAsync(gcur, 0, GCUR_N * sizeof(int), stream);
    bin_edges<<<dim3(NBLK_E), blk, 0, stream>>>(src, dst, gcur, binned);
    build_slots<<<dim3(NB), blk, 0, stream>>>(gcur, binned, deg, slots);

    // ---- layer 1: tmp = x@W_rel1 (bf16, +zero dummy rows); h1 = relu(gather+root) --
    gemm14<<<grd_no, blk, 0, stream>>>(x, W_rel1, B0b, B1b);
    conv_fused<false, IN_DIM, false><<<grd_cv, blk, 0, stream>>>(
        deg, slots, B0b, (const void*)x, nullptr, b_rel1, W_root1, B1b);

    // ---- layers 2..5: h' = relu(gather(h)@W_rel + b + h@W_root) ----
    ushort* cur = B1b;
    ushort* nxt = B0b;
    for (int i = 0; i < 4; ++i) {
        conv_fused<true, HID, true><<<grd_cv, blk, 0, stream>>>(
            deg, slots, cur, (const void*)cur, W_rel + i * HID * HID,
            b_rel + i * HID, W_root + i * HID * HID, nxt);
        ushort* tswap = cur; cur = nxt; nxt = tswap;
    }
    // final h in `cur`

    // ---- sum pool + head ----
    hipMemsetAsync(g, 0, (size_t)N_GRAPHS * HID * sizeof(float), stream);
    pool_sum<<<grd_pl, blk, 0, stream>>>(cur, batch, g);
    head<<<dim3(1), dim3(512), 0, stream>>>(g, lin1_w, lin1_b, lin2_w, lin2_b, out);
}